// Round 7
// baseline (5516.102 us; speedup 1.0000x reference)
//
#include <hip/hip_runtime.h>
#include <hip/hip_cooperative_groups.h>

namespace cg = cooperative_groups;

#define AA 60
#define HH 96
#define WW 96
#define DD 96
#define HWP (HH * WW)   // 9216
#define ADP (AA * DD)   // 5760
#define NITER 10
#define MATEL (60 * 96 * 9216)

typedef unsigned short ushort8 __attribute__((ext_vector_type(8)));
typedef unsigned short ushort4v __attribute__((ext_vector_type(4)));
typedef float float4v __attribute__((ext_vector_type(4)));

__device__ inline float b2f(unsigned short u) {
    return __uint_as_float(((unsigned)u) << 16);
}
__device__ inline unsigned short f2b(float f) {
    unsigned u = __float_as_uint(f);
    u += 0x7FFFu + ((u >> 16) & 1u);
    return (unsigned short)(u >> 16);
}

// ---- norm f32 -> bf16 straight convert (layout preserved) ----
__global__ __launch_bounds__(256) void cvtA_kernel(const float* __restrict__ src,
                                                   ushort8* __restrict__ dst,
                                                   int base, int n8) {
    int i = base + blockIdx.x * 256 + threadIdx.x;
    if (i >= n8) return;
    const float4v* s = reinterpret_cast<const float4v*>(src) + 2 * (size_t)i;
    float4v x = __builtin_nontemporal_load(s);
    float4v y = __builtin_nontemporal_load(s + 1);
    ushort8 o;
    o[0] = f2b(x[0]); o[1] = f2b(x[1]); o[2] = f2b(x[2]); o[3] = f2b(x[3]);
    o[4] = f2b(y[0]); o[5] = f2b(y[1]); o[6] = f2b(y[2]); o[7] = f2b(y[3]);
    dst[i] = o;
}

// ---- sysm f32 [a][v][n] -> bf16 sysmT [a][n][p], v(p)=(p%96)*96+p/96 ----
__global__ __launch_bounds__(256) void cvtB_kernel(const float* __restrict__ sysm,
                                                   unsigned short* __restrict__ sysmT,
                                                   int a_base) {
    __shared__ unsigned short lds[96][132];
    int a  = a_base + blockIdx.y;
    int p0 = blockIdx.x * 128;
    int t  = threadIdx.x;
    int p_local = t >> 1, half = t & 1;
    int p = p0 + p_local;
    int v = (p % 96) * 96 + p / 96;
    const float* srow = sysm + ((size_t)a * HWP + v) * DD + half * 48;
#pragma unroll
    for (int jj = 0; jj < 12; ++jj) {
        float4v x = __builtin_nontemporal_load(reinterpret_cast<const float4v*>(srow) + jj);
        int n = half * 48 + 4 * jj;
        lds[n][p_local]     = f2b(x[0]);
        lds[n + 1][p_local] = f2b(x[1]);
        lds[n + 2][p_local] = f2b(x[2]);
        lds[n + 3][p_local] = f2b(x[3]);
    }
    __syncthreads();
    int l = t & 63, wv = t >> 6;
    unsigned short* obase = sysmT + (size_t)a * DD * HWP + p0;
#pragma unroll
    for (int pass = 0; pass < 24; ++pass) {
        int n = pass * 4 + wv;
        unsigned val = (unsigned)lds[n][2 * l] | ((unsigned)lds[n][2 * l + 1] << 16);
        *reinterpret_cast<unsigned*>(obase + (size_t)n * HWP + 2 * l) = val;
    }
}

__global__ __launch_bounds__(256) void init_kernel(const float* __restrict__ dual,
                            const float* __restrict__ g,
                            const float* __restrict__ primal,
                            float* __restrict__ xd, float* __restrict__ xp,
                            float* __restrict__ imgf, float* __restrict__ xp5) {
    int i = blockIdx.x * 256 + threadIdx.x;
    if (i < ADP) { xd[i] = dual[i]; xd[2 * ADP + i] = g[i]; }
    if (i < 5 * HWP) xp[i] = primal[i];
    if (i < HWP) {
        imgf[(i % WW) * HH + i / WW] = primal[HWP + i];
        xp5[i] = 0.f;
    }
}

struct Prm {
    const unsigned short* normb;
    const unsigned short* sysmT;
    float* xd; float* xp; float* imgf;
    float* h1; float* h2; float* g1; float* g2;
    const float *dw1, *db1, *da1, *dw2, *db2, *da2, *dw3, *db3;
    const float *pw1, *pb1, *pa1, *pw2, *pb2, *pa2, *pw3, *pb3;
    float* dout;
};

// grid-strided 3x3 conv stage (pad=1, PReLU)
template <int CIN, int NOUT>
__device__ void conv_stage(int wid, int nw, int lane,
        const float* in, const float* wgt, const float* bias, float a,
        float* out, int Hc, int Wc, int npb, int nocg) {
    int hw = Hc * Wc;
    int nu = npb * nocg;
    for (int u = wid; u < nu; u += nw) {
        int pblk = u % npb, ocg = u / npb;
        int pix = pblk * 64 + lane;
        int y = pix / Wc, x = pix % Wc;
        int oc0 = ocg * NOUT;
        const float* wb = wgt + (size_t)oc0 * CIN * 9;
        float acc[NOUT];
#pragma unroll
        for (int o = 0; o < NOUT; ++o) acc[o] = bias[oc0 + o];
        for (int ci = 0; ci < CIN; ++ci) {
            const float* ip = in + ci * hw;
#pragma unroll
            for (int ky = 0; ky < 3; ++ky) {
                int yy = y + ky - 1;
                bool yok = (unsigned)yy < (unsigned)Hc;
#pragma unroll
                for (int kx = 0; kx < 3; ++kx) {
                    int xx = x + kx - 1;
                    bool vok = yok && ((unsigned)xx < (unsigned)Wc);
                    float v = ip[vok ? yy * Wc + xx : 0];
                    v = vok ? v : 0.f;
#pragma unroll
                    for (int o = 0; o < NOUT; ++o)
                        acc[o] += wb[(o * CIN + ci) * 9 + ky * 3 + kx] * v;
                }
            }
        }
#pragma unroll
        for (int o = 0; o < NOUT; ++o) {
            float r = acc[o];
            r = (r >= 0.f) ? r : a * r;
            out[(oc0 + o) * hw + pix] = r;
        }
    }
}

__global__ __launch_bounds__(256, 2) void loop_kernel(Prm p) {
    cg::grid_group grid = cg::this_grid();
    int tid  = threadIdx.x;
    int lane = tid & 63;
    int wib  = tid >> 6;
    int wid  = blockIdx.x * 4 + wib;
    int nw   = gridDim.x * 4;

    for (int k = 0; k < NITER; ++k) {
        // ---- S1: einsum1  prod[row]=dot(normb[row,:],imgf) -> xd ch1 ----
        for (int row = wid; row < ADP; row += nw) {
            const unsigned short* mr = p.normb + (size_t)row * HWP;
            float s = 0.f;
            for (int kk = 0; kk < HWP / 512; ++kk) {
                int n = 8 * lane + 512 * kk;
                ushort8 m8 = *reinterpret_cast<const ushort8*>(mr + n);
                float4v i0 = *reinterpret_cast<const float4v*>(p.imgf + n);
                float4v i1 = *reinterpret_cast<const float4v*>(p.imgf + n + 4);
                s += b2f(m8[0]) * i0[0] + b2f(m8[1]) * i0[1] + b2f(m8[2]) * i0[2] + b2f(m8[3]) * i0[3]
                   + b2f(m8[4]) * i1[0] + b2f(m8[5]) * i1[1] + b2f(m8[6]) * i1[2] + b2f(m8[7]) * i1[3];
            }
#pragma unroll
            for (int off = 32; off > 0; off >>= 1) s += __shfl_down(s, off);
            if (lane == 0) p.xd[ADP + row] = s;
        }
        grid.sync();
        // ---- S2: dual conv1 (3->32) ----
        conv_stage<3, 4>(wid, nw, lane, p.xd, p.dw1 + k * 32 * 3 * 9,
                         p.db1 + k * 32, p.da1[k], p.h1, AA, DD, 90, 8);
        grid.sync();
        // ---- S3: dual conv2 (32->32) ----
        conv_stage<32, 4>(wid, nw, lane, p.h1, p.dw2 + k * 32 * 32 * 9,
                          p.db2 + k * 32, p.da2[k], p.h2, AA, DD, 90, 8);
        grid.sync();
        // ---- S4: dual conv3 (32->1) + residual into xd ch0 ----
        for (int u = wid; u < 360; u += nw) {
            int pblk = u % 90, cg8 = u / 90;
            int pix = pblk * 64 + lane;
            int y = pix / DD, x = pix % DD;
            const float* wg = p.dw3 + k * 32 * 9;
            float r = (cg8 == 0) ? p.db3[k] : 0.f;
            for (int ci = cg8 * 8; ci < cg8 * 8 + 8; ++ci) {
                const float* ip = p.h2 + ci * ADP;
#pragma unroll
                for (int ky = 0; ky < 3; ++ky) {
                    int yy = y + ky - 1;
                    bool yok = (unsigned)yy < (unsigned)AA;
#pragma unroll
                    for (int kx = 0; kx < 3; ++kx) {
                        int xx = x + kx - 1;
                        bool vok = yok && ((unsigned)xx < (unsigned)DD);
                        float v = ip[vok ? yy * DD + xx : 0];
                        v = vok ? v : 0.f;
                        r += wg[ci * 9 + ky * 3 + kx] * v;
                    }
                }
            }
            atomicAdd(p.xd + pix, r);
        }
        grid.sync();
        // ---- S5: einsum2  xp5[p] += sum_{a,n} sysmT[a][n][p]*dual[a*96+n] ----
        for (int u = wid; u < 1080; u += nw) {
            int tile = u % 36, ap = u / 36;      // a-pair 0..29
            int p0 = tile * 256 + lane * 4;
            const float* dl = p.xd + ap * 192;   // wave-uniform -> scalar loads
            float c0 = 0.f, c1 = 0.f, c2 = 0.f, c3 = 0.f;
#pragma unroll
            for (int ai = 0; ai < 2; ++ai) {
                const unsigned short* base = p.sysmT + ((size_t)(2 * ap + ai) * DD) * HWP + p0;
#pragma unroll 8
                for (int n = 0; n < DD; ++n) {
                    ushort4v m4 = *reinterpret_cast<const ushort4v*>(base + (size_t)n * HWP);
                    float d = dl[ai * 96 + n];
                    c0 += b2f(m4[0]) * d;
                    c1 += b2f(m4[1]) * d;
                    c2 += b2f(m4[2]) * d;
                    c3 += b2f(m4[3]) * d;
                }
            }
            float* x5 = p.xp + 5 * HWP;
            atomicAdd(x5 + p0,     c0);
            atomicAdd(x5 + p0 + 1, c1);
            atomicAdd(x5 + p0 + 2, c2);
            atomicAdd(x5 + p0 + 3, c3);
        }
        grid.sync();
        // ---- S6: primal conv1 (6->32) ----
        conv_stage<6, 4>(wid, nw, lane, p.xp, p.pw1 + k * 32 * 6 * 9,
                         p.pb1 + k * 32, p.pa1[k], p.g1, HH, WW, 144, 8);
        grid.sync();
        // ---- S7: primal conv2 (32->32) ----
        conv_stage<32, 4>(wid, nw, lane, p.g1, p.pw2 + k * 32 * 32 * 9,
                          p.pb2 + k * 32, p.pa2[k], p.g2, HH, WW, 144, 8);
        grid.sync();
        // ---- S8: primal conv3 (32->5) + residual + imgf + xp5-zero + dout ----
        for (int u = wid; u < 720; u += nw) {
            int pblk = u % 144, oc = u / 144;
            int pix = pblk * 64 + lane;
            int y = pix / WW, x = pix % WW;
            const float* wb = p.pw3 + k * 5 * 32 * 9 + (size_t)oc * 32 * 9;
            float r = p.pb3[k * 5 + oc];
            for (int ci = 0; ci < 32; ++ci) {
                const float* ip = p.g2 + ci * HWP;
#pragma unroll
                for (int ky = 0; ky < 3; ++ky) {
                    int yy = y + ky - 1;
                    bool yok = (unsigned)yy < (unsigned)HH;
#pragma unroll
                    for (int kx = 0; kx < 3; ++kx) {
                        int xx = x + kx - 1;
                        bool vok = yok && ((unsigned)xx < (unsigned)WW);
                        float v = ip[vok ? yy * WW + xx : 0];
                        v = vok ? v : 0.f;
                        r += wb[ci * 9 + ky * 3 + kx] * v;
                    }
                }
            }
            float nv = p.xp[oc * HWP + pix] + r;
            p.xp[oc * HWP + pix] = nv;
            if (oc == 1) p.imgf[x * HH + y] = nv;
            if (oc == 2) p.xp[5 * HWP + pix] = 0.f;
            if (k == NITER - 1 && oc == 0) p.dout[pix] = nv;
        }
        grid.sync();
    }
}

// ================= fallback path (round-5 kernels, known-good) =================
__global__ __launch_bounds__(256) void einsum1_kernel(const unsigned short* __restrict__ norm,
                               const float* __restrict__ imgf,
                               float* __restrict__ out) {
    int row  = blockIdx.x * 4 + (threadIdx.x >> 6);
    int lane = threadIdx.x & 63;
    const unsigned short* mr = norm + (size_t)row * HWP;
    float s = 0.f;
    for (int k = 0; k < HWP / 512; ++k) {
        int n = 8 * lane + 512 * k;
        ushort8 m8 = *reinterpret_cast<const ushort8*>(mr + n);
        float4v i0 = *reinterpret_cast<const float4v*>(imgf + n);
        float4v i1 = *reinterpret_cast<const float4v*>(imgf + n + 4);
        s += b2f(m8[0]) * i0[0] + b2f(m8[1]) * i0[1] + b2f(m8[2]) * i0[2] + b2f(m8[3]) * i0[3]
           + b2f(m8[4]) * i1[0] + b2f(m8[5]) * i1[1] + b2f(m8[6]) * i1[2] + b2f(m8[7]) * i1[3];
    }
#pragma unroll
    for (int off = 32; off > 0; off >>= 1) s += __shfl_down(s, off);
    if (lane == 0) out[row] = s;
}

__global__ __launch_bounds__(64) void einsum2_kernel(const unsigned short* __restrict__ sysmT,
                               const float* __restrict__ xd,
                               float* __restrict__ xp5) {
    __shared__ float sd[4 * DD];
    int t  = threadIdx.x;
    int a0 = blockIdx.y * 4;
    int p0 = blockIdx.x * 256 + t * 4;
    for (int j = t; j < 4 * DD; j += 64) sd[j] = xd[a0 * DD + j];
    __syncthreads();
    float a0c = 0.f, a1c = 0.f, a2c = 0.f, a3c = 0.f;
    for (int ai = 0; ai < 4; ++ai) {
        const unsigned short* base = sysmT + ((size_t)(a0 + ai) * DD) * HWP + p0;
        const float* dl = sd + ai * DD;
#pragma unroll 8
        for (int n = 0; n < DD; ++n) {
            ushort4v m4 = *reinterpret_cast<const ushort4v*>(base + (size_t)n * HWP);
            float d = dl[n];
            a0c += b2f(m4[0]) * d;
            a1c += b2f(m4[1]) * d;
            a2c += b2f(m4[2]) * d;
            a3c += b2f(m4[3]) * d;
        }
    }
    atomicAdd(xp5 + p0,     a0c);
    atomicAdd(xp5 + p0 + 1, a1c);
    atomicAdd(xp5 + p0 + 2, a2c);
    atomicAdd(xp5 + p0 + 3, a3c);
}

template <int CIN, int NOUT>
__global__ __launch_bounds__(64) void conv_mid(
        const float* __restrict__ in, const float* __restrict__ wgt,
        const float* __restrict__ bias, const float* __restrict__ alpha,
        float* __restrict__ out, int Hc, int Wc) {
    int hw  = Hc * Wc;
    int pix = blockIdx.x * 64 + threadIdx.x;
    int y = pix / Wc, x = pix % Wc;
    int oc0 = blockIdx.y * NOUT;
    const float* wb = wgt + (size_t)oc0 * CIN * 9;
    float a = alpha[0];
    float acc[NOUT];
#pragma unroll
    for (int o = 0; o < NOUT; ++o) acc[o] = bias[oc0 + o];
    for (int ci = 0; ci < CIN; ++ci) {
        const float* ip = in + ci * hw;
#pragma unroll
        for (int ky = 0; ky < 3; ++ky) {
            int yy = y + ky - 1;
            bool yok = (unsigned)yy < (unsigned)Hc;
#pragma unroll
            for (int kx = 0; kx < 3; ++kx) {
                int xx = x + kx - 1;
                bool vok = yok && ((unsigned)xx < (unsigned)Wc);
                float v = ip[vok ? yy * Wc + xx : 0];
                v = vok ? v : 0.f;
#pragma unroll
                for (int o = 0; o < NOUT; ++o)
                    acc[o] += wb[(o * CIN + ci) * 9 + ky * 3 + kx] * v;
            }
        }
    }
#pragma unroll
    for (int o = 0; o < NOUT; ++o) {
        float r = acc[o];
        r = (r >= 0.f) ? r : a * r;
        out[(oc0 + o) * hw + pix] = r;
    }
}

__global__ __launch_bounds__(64) void conv3d_last(const float* __restrict__ in,
        const float* __restrict__ wgt, const float* __restrict__ bias,
        float* __restrict__ xd) {
    int pix = blockIdx.x * 64 + threadIdx.x;
    int y = pix / DD, x = pix % DD;
    int c0 = blockIdx.y * 8;
    float r = (blockIdx.y == 0) ? bias[0] : 0.f;
    for (int ci = c0; ci < c0 + 8; ++ci) {
        const float* ip = in + ci * ADP;
#pragma unroll
        for (int ky = 0; ky < 3; ++ky) {
            int yy = y + ky - 1;
            bool yok = (unsigned)yy < (unsigned)AA;
#pragma unroll
            for (int kx = 0; kx < 3; ++kx) {
                int xx = x + kx - 1;
                bool vok = yok && ((unsigned)xx < (unsigned)DD);
                float v = ip[vok ? yy * DD + xx : 0];
                v = vok ? v : 0.f;
                r += wgt[ci * 9 + ky * 3 + kx] * v;
            }
        }
    }
    atomicAdd(xd + pix, r);
}

__global__ __launch_bounds__(64) void conv3p_last(const float* __restrict__ in,
        const float* __restrict__ wgt, const float* __restrict__ bias,
        float* __restrict__ xp, float* __restrict__ imgf,
        float* __restrict__ xp5, float* __restrict__ dout, int fin) {
    int pix = blockIdx.x * 64 + threadIdx.x;
    int y = pix / WW, x = pix % WW;
    int oc = blockIdx.y;
    const float* wb = wgt + (size_t)oc * 32 * 9;
    float r = bias[oc];
    for (int ci = 0; ci < 32; ++ci) {
        const float* ip = in + ci * HWP;
#pragma unroll
        for (int ky = 0; ky < 3; ++ky) {
            int yy = y + ky - 1;
            bool yok = (unsigned)yy < (unsigned)HH;
#pragma unroll
            for (int kx = 0; kx < 3; ++kx) {
                int xx = x + kx - 1;
                bool vok = yok && ((unsigned)xx < (unsigned)WW);
                float v = ip[vok ? yy * WW + xx : 0];
                v = vok ? v : 0.f;
                r += wb[ci * 9 + ky * 3 + kx] * v;
            }
        }
    }
    float nv = xp[oc * HWP + pix] + r;
    xp[oc * HWP + pix] = nv;
    if (oc == 1) imgf[x * HH + y] = nv;
    if (oc == 2) xp5[pix] = 0.f;
    if (fin && oc == 0) dout[pix] = nv;
}

extern "C" void kernel_launch(void* const* d_in, const int* in_sizes, int n_in,
                              void* d_out, int out_size, void* d_ws, size_t ws_size,
                              hipStream_t stream) {
    const float* dual   = (const float*)d_in[0];
    const float* primal = (const float*)d_in[1];
    const float* g      = (const float*)d_in[2];
    const float* sysm   = (const float*)d_in[3];
    const float* norm   = (const float*)d_in[4];

    unsigned short* normb = (unsigned short*)d_ws;     // [row][n] bf16
    unsigned short* sysmT = normb + MATEL;             // [a][n][p] bf16
    float* xd   = (float*)(sysmT + MATEL);
    float* xp   = xd + 3 * ADP;
    float* imgf = xp + 6 * HWP;
    float* h1   = imgf + HWP;
    float* h2   = h1 + 32 * ADP;
    float* g1   = h2 + 32 * ADP;
    float* g2   = g1 + 32 * HWP;

    const int N8 = MATEL / 8;
    const int CHK = N8 / 4;
    for (int c = 0; c < 4; ++c)
        cvtA_kernel<<<CHK / 256, 256, 0, stream>>>(norm, (ushort8*)normb, c * CHK, N8);
    for (int c = 0; c < 5; ++c)
        cvtB_kernel<<<dim3(HWP / 128, 12), 256, 0, stream>>>(sysm, sysmT, c * 12);
    init_kernel<<<(5 * HWP + 255) / 256, 256, 0, stream>>>(dual, g, primal, xd, xp, imgf, xp + 5 * HWP);

    Prm prm;
    prm.normb = normb; prm.sysmT = sysmT;
    prm.xd = xd; prm.xp = xp; prm.imgf = imgf;
    prm.h1 = h1; prm.h2 = h2; prm.g1 = g1; prm.g2 = g2;
    prm.dw1 = (const float*)d_in[5];  prm.db1 = (const float*)d_in[6];
    prm.da1 = (const float*)d_in[7];  prm.dw2 = (const float*)d_in[8];
    prm.db2 = (const float*)d_in[9];  prm.da2 = (const float*)d_in[10];
    prm.dw3 = (const float*)d_in[11]; prm.db3 = (const float*)d_in[12];
    prm.pw1 = (const float*)d_in[13]; prm.pb1 = (const float*)d_in[14];
    prm.pa1 = (const float*)d_in[15]; prm.pw2 = (const float*)d_in[16];
    prm.pb2 = (const float*)d_in[17]; prm.pa2 = (const float*)d_in[18];
    prm.pw3 = (const float*)d_in[19]; prm.pb3 = (const float*)d_in[20];
    prm.dout = (float*)d_out;

    // ---- try cooperative persistent loop with occupancy margin ----
    bool coop_done = false;
    int nCU = 0, maxB = 0, dev = 0;
    (void)hipGetDevice(&dev);
    if (hipDeviceGetAttribute(&nCU, hipDeviceAttributeMultiprocessorCount, dev) == hipSuccess &&
        hipOccupancyMaxActiveBlocksPerMultiprocessor(&maxB, (const void*)loop_kernel, 256, 0) == hipSuccess &&
        nCU > 0 && maxB > 0) {
        long cap = (long)maxB * nCU;
        int nblk = (int)(cap < 512 ? cap : 512);
        if (nblk >= 64) {
            void* args[] = { &prm };
            if (hipLaunchCooperativeKernel((void*)loop_kernel, dim3(nblk), dim3(256),
                                           args, 0, stream) == hipSuccess)
                coop_done = true;
        }
    }

    if (!coop_done) {
        // fallback: round-5 multi-kernel path
        const float* dw1 = prm.dw1; const float* db1 = prm.db1; const float* da1 = prm.da1;
        const float* dw2 = prm.dw2; const float* db2 = prm.db2; const float* da2 = prm.da2;
        const float* dw3 = prm.dw3; const float* db3 = prm.db3;
        const float* pw1 = prm.pw1; const float* pb1 = prm.pb1; const float* pa1 = prm.pa1;
        const float* pw2 = prm.pw2; const float* pb2 = prm.pb2; const float* pa2 = prm.pa2;
        const float* pw3 = prm.pw3; const float* pb3 = prm.pb3;
        for (int k = 0; k < NITER; ++k) {
            einsum1_kernel<<<ADP / 4, 256, 0, stream>>>(normb, imgf, xd + ADP);
            conv_mid<3, 4><<<dim3(ADP / 64, 8), 64, 0, stream>>>(
                xd, dw1 + k * 32 * 3 * 9, db1 + k * 32, da1 + k, h1, AA, DD);
            conv_mid<32, 4><<<dim3(ADP / 64, 8), 64, 0, stream>>>(
                h1, dw2 + k * 32 * 32 * 9, db2 + k * 32, da2 + k, h2, AA, DD);
            conv3d_last<<<dim3(ADP / 64, 4), 64, 0, stream>>>(
                h2, dw3 + k * 32 * 9, db3 + k, xd);
            einsum2_kernel<<<dim3(HWP / 256, 15), 64, 0, stream>>>(sysmT, xd, xp + 5 * HWP);
            conv_mid<6, 4><<<dim3(HWP / 64, 8), 64, 0, stream>>>(
                xp, pw1 + k * 32 * 6 * 9, pb1 + k * 32, pa1 + k, g1, HH, WW);
            conv_mid<32, 4><<<dim3(HWP / 64, 8), 64, 0, stream>>>(
                g1, pw2 + k * 32 * 32 * 9, pb2 + k * 32, pa2 + k, g2, HH, WW);
            conv3p_last<<<dim3(HWP / 64, 5), 64, 0, stream>>>(
                g2, pw3 + k * 5 * 32 * 9, pb3 + k * 5, xp, imgf, xp + 5 * HWP,
                (float*)d_out, k == NITER - 1 ? 1 : 0);
        }
    }
}

// Round 8
// 1095.963 us; speedup vs baseline: 5.0331x; 5.0331x over previous
//
#include <hip/hip_runtime.h>

#define AA 60
#define HH 96
#define WW 96
#define DD 96
#define HWP (HH * WW)   // 9216
#define ADP (AA * DD)   // 5760
#define NITER 10
#define MATEL (60 * 96 * 9216)   // 53,084,160 elements per system matrix

typedef unsigned short ushort8 __attribute__((ext_vector_type(8)));
typedef float float4v __attribute__((ext_vector_type(4)));

__device__ inline float b2f(unsigned short u) {
    return __uint_as_float(((unsigned)u) << 16);
}
__device__ inline unsigned short f2b(float f) {
    unsigned u = __float_as_uint(f);
    u += 0x7FFFu + ((u >> 16) & 1u);
    return (unsigned short)(u >> 16);
}

// ---- f32 -> bf16 conversion of both system matrices (once per call) ----
__global__ __launch_bounds__(256) void cvt_kernel(const float* __restrict__ a,
                                                  const float* __restrict__ b,
                                                  ushort8* __restrict__ da,
                                                  ushort8* __restrict__ db, int n8) {
    int stride = gridDim.x * 256;
    for (int i = blockIdx.x * 256 + threadIdx.x; i < 2 * n8; i += stride) {
        const float* src; ushort8* dst; int j;
        if (i < n8) { src = a; dst = da; j = i; }
        else        { src = b; dst = db; j = i - n8; }
        const float4v* s = reinterpret_cast<const float4v*>(src) + 2 * (size_t)j;
        float4v x = __builtin_nontemporal_load(s);
        float4v y = __builtin_nontemporal_load(s + 1);
        ushort8 o;
        o[0] = f2b(x[0]); o[1] = f2b(x[1]); o[2] = f2b(x[2]); o[3] = f2b(x[3]);
        o[4] = f2b(y[0]); o[5] = f2b(y[1]); o[6] = f2b(y[2]); o[7] = f2b(y[3]);
        dst[j] = o;
    }
}

// xd[3][5760]: ch0=dual, ch1=evalop1, ch2=g ; xp[6][9216]: ch0..4=p2d, ch5=evalop2
__global__ __launch_bounds__(256) void init_kernel(const float* __restrict__ dual,
                            const float* __restrict__ g,
                            const float* __restrict__ primal,
                            float* __restrict__ xd, float* __restrict__ xp,
                            float* __restrict__ imgf, float* __restrict__ xp5) {
    int i = blockIdx.x * 256 + threadIdx.x;
    if (i < ADP) { xd[i] = dual[i]; xd[2 * ADP + i] = g[i]; }
    if (i < 5 * HWP) xp[i] = primal[i];
    if (i < HWP) {
        imgf[(i % WW) * HH + i / WW] = primal[HWP + i];
        xp5[i] = 0.f;
    }
}

// prod[row] = dot(norm_bf16[row,:9216], imgf); one wave per row
__global__ __launch_bounds__(256) void einsum1_kernel(const unsigned short* __restrict__ norm,
                               const float* __restrict__ imgf,
                               float* __restrict__ out) {
    int row  = blockIdx.x * 4 + (threadIdx.x >> 6);
    int lane = threadIdx.x & 63;
    const unsigned short* mr = norm + (size_t)row * HWP;
    float s = 0.f;
    for (int k = 0; k < HWP / 512; ++k) {   // 18 iters
        int n = 8 * lane + 512 * k;
        ushort8 m8 = *reinterpret_cast<const ushort8*>(mr + n);
        float4 i0 = *reinterpret_cast<const float4*>(imgf + n);
        float4 i1 = *reinterpret_cast<const float4*>(imgf + n + 4);
        s += b2f(m8[0]) * i0.x + b2f(m8[1]) * i0.y + b2f(m8[2]) * i0.z + b2f(m8[3]) * i0.w
           + b2f(m8[4]) * i1.x + b2f(m8[5]) * i1.y + b2f(m8[6]) * i1.z + b2f(m8[7]) * i1.w;
    }
#pragma unroll
    for (int off = 32; off > 0; off >>= 1) s += __shfl_down(s, off);
    if (lane == 0) out[row] = s;
}

// vec[v] = sum_{a,n} sysm_bf16[a,v,n]*dual[a,n]; fortran-transposed scatter
__global__ __launch_bounds__(256) void einsum2_kernel(const unsigned short* __restrict__ sysm,
                               const float* __restrict__ xd,
                               float* __restrict__ xp5) {
    __shared__ float sd[4 * DD];
    int t  = threadIdx.x;
    int a0 = (blockIdx.x % 15) * 4;
    int v  = (blockIdx.x / 15) * 256 + t;
    for (int j = t; j < 4 * DD; j += 256) sd[j] = xd[a0 * DD + j];
    __syncthreads();
    float s = 0.f;
    for (int ai = 0; ai < 4; ++ai) {
        const unsigned short* row = sysm + ((size_t)(a0 + ai) * HWP + v) * DD;
        const float* dl = sd + ai * DD;
#pragma unroll
        for (int jj = 0; jj < DD / 8; ++jj) {
            ushort8 m8 = *reinterpret_cast<const ushort8*>(row + 8 * jj);
            s += b2f(m8[0]) * dl[8 * jj]     + b2f(m8[1]) * dl[8 * jj + 1]
               + b2f(m8[2]) * dl[8 * jj + 2] + b2f(m8[3]) * dl[8 * jj + 3]
               + b2f(m8[4]) * dl[8 * jj + 4] + b2f(m8[5]) * dl[8 * jj + 5]
               + b2f(m8[6]) * dl[8 * jj + 6] + b2f(m8[7]) * dl[8 * jj + 7];
        }
    }
    atomicAdd(xp5 + (v % HH) * WW + (v / HH), s);
}

// 3x3 conv pad=1, PReLU. Grid: (hw/64, Cout/NOUT), block 64.
template <int CIN, int NOUT>
__global__ __launch_bounds__(64) void conv_mid(
        const float* __restrict__ in,
        const float* __restrict__ wgt,   // [Cout][CIN][3][3]
        const float* __restrict__ bias,
        const float* __restrict__ alpha,
        float* __restrict__ out,
        int Hc, int Wc) {
    int hw  = Hc * Wc;
    int pix = blockIdx.x * 64 + threadIdx.x;
    int y = pix / Wc, x = pix % Wc;
    int oc0 = blockIdx.y * NOUT;
    const float* wb = wgt + (size_t)oc0 * CIN * 9;
    float a = alpha[0];
    float acc[NOUT];
#pragma unroll
    for (int o = 0; o < NOUT; ++o) acc[o] = bias[oc0 + o];
    for (int ci = 0; ci < CIN; ++ci) {
        const float* ip = in + ci * hw;
#pragma unroll
        for (int ky = 0; ky < 3; ++ky) {
            int yy = y + ky - 1;
            bool yok = (unsigned)yy < (unsigned)Hc;
#pragma unroll
            for (int kx = 0; kx < 3; ++kx) {
                int xx = x + kx - 1;
                bool vok = yok && ((unsigned)xx < (unsigned)Wc);
                float v = ip[vok ? yy * Wc + xx : 0];
                v = vok ? v : 0.f;
#pragma unroll
                for (int o = 0; o < NOUT; ++o)
                    acc[o] += wb[(o * CIN + ci) * 9 + ky * 3 + kx] * v;
            }
        }
    }
#pragma unroll
    for (int o = 0; o < NOUT; ++o) {
        float r = acc[o];
        r = (r >= 0.f) ? r : a * r;
        out[(oc0 + o) * hw + pix] = r;
    }
}

// dual conv3 (32->1) + residual into xd ch0, split over ci-chunks of 4 (atomicAdd)
__global__ __launch_bounds__(64) void conv3d_last(const float* __restrict__ in,
        const float* __restrict__ wgt,   // [32][9]
        const float* __restrict__ bias,  // [1]
        float* __restrict__ xd) {
    int pix = blockIdx.x * 64 + threadIdx.x;   // 0..5759
    int y = pix / DD, x = pix % DD;
    int c0 = blockIdx.y * 4;
    float r = (blockIdx.y == 0) ? bias[0] : 0.f;
    for (int ci = c0; ci < c0 + 4; ++ci) {
        const float* ip = in + ci * ADP;
#pragma unroll
        for (int ky = 0; ky < 3; ++ky) {
            int yy = y + ky - 1;
            bool yok = (unsigned)yy < (unsigned)AA;
#pragma unroll
            for (int kx = 0; kx < 3; ++kx) {
                int xx = x + kx - 1;
                bool vok = yok && ((unsigned)xx < (unsigned)DD);
                float v = ip[vok ? yy * DD + xx : 0];
                v = vok ? v : 0.f;
                r += wgt[ci * 9 + ky * 3 + kx] * v;
            }
        }
    }
    atomicAdd(xd + pix, r);
}

// primal conv3 (32->5) + residual into xp; fused: imgf for next iter (ch1),
// xp5 zero (ch2 block), final output write (ch0 block, last iter)
__global__ __launch_bounds__(64) void conv3p_last(const float* __restrict__ in,
        const float* __restrict__ wgt,   // [5][32][9]
        const float* __restrict__ bias,  // [5]
        float* __restrict__ xp, float* __restrict__ imgf,
        float* __restrict__ xp5, float* __restrict__ dout, int fin) {
    int pix = blockIdx.x * 64 + threadIdx.x;   // 0..9215
    int y = pix / WW, x = pix % WW;
    int oc = blockIdx.y;                       // 0..4
    const float* wb = wgt + (size_t)oc * 32 * 9;
    float r = bias[oc];
    for (int ci = 0; ci < 32; ++ci) {
        const float* ip = in + ci * HWP;
#pragma unroll
        for (int ky = 0; ky < 3; ++ky) {
            int yy = y + ky - 1;
            bool yok = (unsigned)yy < (unsigned)HH;
#pragma unroll
            for (int kx = 0; kx < 3; ++kx) {
                int xx = x + kx - 1;
                bool vok = yok && ((unsigned)xx < (unsigned)WW);
                float v = ip[vok ? yy * WW + xx : 0];
                v = vok ? v : 0.f;
                r += wb[ci * 9 + ky * 3 + kx] * v;
            }
        }
    }
    float nv = xp[oc * HWP + pix] + r;
    xp[oc * HWP + pix] = nv;
    if (oc == 1) imgf[x * HH + y] = nv;    // fortran flatten for next einsum1
    if (oc == 2) xp5[pix] = 0.f;           // clear evalop2 accumulator
    if (fin && oc == 0) dout[pix] = nv;    // final output
}

extern "C" void kernel_launch(void* const* d_in, const int* in_sizes, int n_in,
                              void* d_out, int out_size, void* d_ws, size_t ws_size,
                              hipStream_t stream) {
    const float* dual   = (const float*)d_in[0];
    const float* primal = (const float*)d_in[1];
    const float* g      = (const float*)d_in[2];
    const float* sysm   = (const float*)d_in[3];
    const float* norm   = (const float*)d_in[4];
    const float* dw1 = (const float*)d_in[5];
    const float* db1 = (const float*)d_in[6];
    const float* da1 = (const float*)d_in[7];
    const float* dw2 = (const float*)d_in[8];
    const float* db2 = (const float*)d_in[9];
    const float* da2 = (const float*)d_in[10];
    const float* dw3 = (const float*)d_in[11];
    const float* db3 = (const float*)d_in[12];
    const float* pw1 = (const float*)d_in[13];
    const float* pb1 = (const float*)d_in[14];
    const float* pa1 = (const float*)d_in[15];
    const float* pw2 = (const float*)d_in[16];
    const float* pb2 = (const float*)d_in[17];
    const float* pa2 = (const float*)d_in[18];
    const float* pw3 = (const float*)d_in[19];
    const float* pb3 = (const float*)d_in[20];

    unsigned short* normb = (unsigned short*)d_ws;     // MATEL bf16 [row][n]
    unsigned short* sysmb = normb + MATEL;             // MATEL bf16 [a][v][n]
    float* xd   = (float*)(sysmb + MATEL);             // 3*5760
    float* xp   = xd + 3 * ADP;                        // 6*9216
    float* imgf = xp + 6 * HWP;                        // 9216
    float* h1   = imgf + HWP;                          // 32*5760
    float* h2   = h1 + 32 * ADP;                       // 32*5760
    float* g1   = h2 + 32 * ADP;                       // 32*9216
    float* g2   = g1 + 32 * HWP;                       // 32*9216

    cvt_kernel<<<4096, 256, 0, stream>>>(norm, sysm, (ushort8*)normb, (ushort8*)sysmb, MATEL / 8);
    init_kernel<<<(5 * HWP + 255) / 256, 256, 0, stream>>>(dual, g, primal, xd, xp, imgf, xp + 5 * HWP);

    for (int k = 0; k < NITER; ++k) {
        // ---- dual half ----
        einsum1_kernel<<<ADP / 4, 256, 0, stream>>>(normb, imgf, xd + ADP);
        conv_mid<3, 2><<<dim3(ADP / 64, 16), 64, 0, stream>>>(
            xd, dw1 + k * 32 * 3 * 9, db1 + k * 32, da1 + k, h1, AA, DD);
        conv_mid<32, 2><<<dim3(ADP / 64, 16), 64, 0, stream>>>(
            h1, dw2 + k * 32 * 32 * 9, db2 + k * 32, da2 + k, h2, AA, DD);
        conv3d_last<<<dim3(ADP / 64, 8), 64, 0, stream>>>(
            h2, dw3 + k * 32 * 9, db3 + k, xd);
        // ---- primal half ----
        einsum2_kernel<<<15 * 36, 256, 0, stream>>>(sysmb, xd, xp + 5 * HWP);
        conv_mid<6, 2><<<dim3(HWP / 64, 16), 64, 0, stream>>>(
            xp, pw1 + k * 32 * 6 * 9, pb1 + k * 32, pa1 + k, g1, HH, WW);
        conv_mid<32, 2><<<dim3(HWP / 64, 16), 64, 0, stream>>>(
            g1, pw2 + k * 32 * 32 * 9, pb2 + k * 32, pa2 + k, g2, HH, WW);
        conv3p_last<<<dim3(HWP / 64, 5), 64, 0, stream>>>(
            g2, pw3 + k * 5 * 32 * 9, pb3 + k * 5, xp, imgf, xp + 5 * HWP,
            (float*)d_out, k == NITER - 1 ? 1 : 0);
    }
}